// Round 1
// 240.637 us; speedup vs baseline: 1.0025x; 1.0025x over previous
//
#include <hip/hip_runtime.h>

#define BB 16
#define FF 256
#define TT 8192
#define F_CHUNK 8
#define ROWS (F_CHUNK + 2)
#define THREADS 256

__device__ __forceinline__ int sgn_bit(float x) {
    return (int)(__float_as_uint(x) >> 31);
}

// phase(x) = 0 for x>=0, pi for x<0  ->  adj code a = s(next) - s(cur) in {-1,0,1}
// out[g,t] = (a[g-1,t]==+1 ? in[g-1,t] : 0)
//          + (a[g,t]==0 || (g==0 && a<0) || (g==FF-1 && a>0) ? in[g,t] : 0)
//          + (a[g+1,t]==-1 ? in[g+1,t] : 0)
__global__ __launch_bounds__(THREADS, 8) void sst_kernel(const float* __restrict__ in,
                                                         float* __restrict__ out) {
    const int t  = blockIdx.x * (THREADS * 4) + threadIdx.x * 4;
    const int fs = blockIdx.y * F_CHUNK;
    const int b  = blockIdx.z;

    const float* src = in  + (size_t)b * FF * TT + t;
    float*       dst = out + (size_t)b * FF * TT + t;

    const bool tail = (t + 4 >= TT);   // thread owning t = TT-4: adj at TT-1 is 0 (jnp.pad)
    const int  eoff = tail ? 3 : 4;    // clamp next-elem load in-row; value unused when tail

    float4   v[ROWS];
    float    e[ROWS];
    unsigned pk[ROWS];

    // ---- phase 1: issue ALL loads up front (10x dwordx4 + 10x dword = deep MLP) ----
    #pragma unroll
    for (int i = 0; i < ROWS; ++i) {
        const int f = fs - 1 + i;
        if (f >= 0 && f < FF) {
            const float* p = src + (size_t)f * TT;
            v[i] = *reinterpret_cast<const float4*>(p);
            e[i] = p[eoff];                      // next-element sign carrier (L1-hit)
        } else {
            // halo row absent: zero values => zero contribution regardless of code
            v[i] = make_float4(0.f, 0.f, 0.f, 0.f);
            e[i] = 0.f;
        }
    }

    // ---- phase 2: pack per-row adj codes into one u32 (2-bit fields, bias +1) ----
    // field meaning: 0 -> a=-1, 1 -> a=0, 2 -> a=+1
    #pragma unroll
    for (int i = 0; i < ROWS; ++i) {
        const int s0 = sgn_bit(v[i].x), s1 = sgn_bit(v[i].y),
                  s2 = sgn_bit(v[i].z), s3 = sgn_bit(v[i].w), s4 = sgn_bit(e[i]);
        const int a0 = s1 - s0 + 1;
        const int a1 = s2 - s1 + 1;
        const int a2 = s3 - s2 + 1;
        const int a3 = tail ? 1 : (s4 - s3 + 1);
        pk[i] = (unsigned)(a0 | (a1 << 2) | (a2 << 4) | (a3 << 6));
    }

    // ---- phase 3: compute + store the 8 output rows ----
    #pragma unroll
    for (int i = 1; i <= F_CHUNK; ++i) {
        const int g = fs + (i - 1);
        const bool isFirst = (g == 0);
        const bool isLast  = (g == FF - 1);

        const unsigned pp = pk[i - 1], pc = pk[i], pn = pk[i + 1];
        const float4   vp = v[i - 1],  vc = v[i],  vn = v[i + 1];

        float4 r;
        {
            const unsigned cp = pp & 3u, cc = pc & 3u, cn = pn & 3u;
            const bool bc = (cc == 1u) || (isFirst && cc == 0u) || (isLast && cc == 2u);
            r.x = ((cp == 2u) ? vp.x : 0.f) + (bc ? vc.x : 0.f) + ((cn == 0u) ? vn.x : 0.f);
        }
        {
            const unsigned cp = (pp >> 2) & 3u, cc = (pc >> 2) & 3u, cn = (pn >> 2) & 3u;
            const bool bc = (cc == 1u) || (isFirst && cc == 0u) || (isLast && cc == 2u);
            r.y = ((cp == 2u) ? vp.y : 0.f) + (bc ? vc.y : 0.f) + ((cn == 0u) ? vn.y : 0.f);
        }
        {
            const unsigned cp = (pp >> 4) & 3u, cc = (pc >> 4) & 3u, cn = (pn >> 4) & 3u;
            const bool bc = (cc == 1u) || (isFirst && cc == 0u) || (isLast && cc == 2u);
            r.z = ((cp == 2u) ? vp.z : 0.f) + (bc ? vc.z : 0.f) + ((cn == 0u) ? vn.z : 0.f);
        }
        {
            const unsigned cp = (pp >> 6) & 3u, cc = (pc >> 6) & 3u, cn = (pn >> 6) & 3u;
            const bool bc = (cc == 1u) || (isFirst && cc == 0u) || (isLast && cc == 2u);
            r.w = ((cp == 2u) ? vp.w : 0.f) + (bc ? vc.w : 0.f) + ((cn == 0u) ? vn.w : 0.f);
        }

        *reinterpret_cast<float4*>(dst + (size_t)g * TT) = r;
    }
}

extern "C" void kernel_launch(void* const* d_in, const int* in_sizes, int n_in,
                              void* d_out, int out_size, void* d_ws, size_t ws_size,
                              hipStream_t stream) {
    const float* in  = (const float*)d_in[0];
    float*       out = (float*)d_out;
    // grid: (t-blocks, f-chunks, batch) = (8, 32, 16) -> 4096 blocks (16/CU)
    dim3 grid(TT / (THREADS * 4), FF / F_CHUNK, BB);
    sst_kernel<<<grid, THREADS, 0, stream>>>(in, out);
}

// Round 3
// 236.673 us; speedup vs baseline: 1.0193x; 1.0167x over previous
//
#include <hip/hip_runtime.h>

typedef float f32x4 __attribute__((ext_vector_type(4)));

#define BB 16
#define FF 256
#define TT 8192
#define F_CHUNK 8
#define ROWS (F_CHUNK + 2)
#define THREADS 256

__device__ __forceinline__ int sgn_bit(float x) {
    return (int)(__float_as_uint(x) >> 31);
}

// phase(x) = 0 for x>=0, pi for x<0  ->  adj code a = s(next) - s(cur) in {-1,0,1}
// out[g,t] = (a[g-1,t]==+1 ? in[g-1,t] : 0)
//          + (a[g,t]==0 || (g==0 && a<0) || (g==FF-1 && a>0) ? in[g,t] : 0)
//          + (a[g+1,t]==-1 ? in[g+1,t] : 0)
__global__ __launch_bounds__(THREADS, 6) void sst_kernel(const float* __restrict__ in,
                                                         float* __restrict__ out) {
    const int t  = blockIdx.x * (THREADS * 4) + threadIdx.x * 4;
    const int fs = blockIdx.y * F_CHUNK;
    const int b  = blockIdx.z;

    const float* src = in  + (size_t)b * FF * TT + t;
    float*       dst = out + (size_t)b * FF * TT + t;

    const bool tail = (t + 4 >= TT);   // thread owning t = TT-4: adj at TT-1 is 0 (jnp.pad)
    const int  eoff = tail ? 3 : 4;    // clamp next-elem load in-row; value unused when tail

    f32x4    v[ROWS];
    float    e[ROWS];
    unsigned pk[ROWS];

    // ---- phase 1: issue ALL loads (straight-line; rows clamped in-bounds).
    // 10x dwordx4 + 10x dword = 12.8 KB/wave in flight once the fence below pins them.
    #pragma unroll
    for (int i = 0; i < ROWS; ++i) {
        int f = fs - 1 + i;
        f = f < 0 ? 0 : (f > FF - 1 ? FF - 1 : f);   // clamped: halo rows re-read edge row
        const float* p = src + (size_t)f * TT;
        v[i] = *reinterpret_cast<const f32x4*>(p);
        e[i] = p[eoff];                              // next-elem sign carrier (same L1 lines)
    }

    // ---- fence: no load may be sunk below this point (m141: sched_barrier pins order).
    // The compiler still inserts its own counted vmcnt(N) waits before each first use.
    __builtin_amdgcn_sched_barrier(0);

    // ---- phase 2: pack per-row adj codes into one u32 (2-bit fields, bias +1).
    // field meaning: 0 -> a=-1, 1 -> a=0, 2 -> a=+1
    // Halo rows (f out of range) get sentinel 0x55 (all fields 1): as a prev-row it never
    // matches +1, as a next-row it never matches -1, so the clamped garbage never contributes.
    #pragma unroll
    for (int i = 0; i < ROWS; ++i) {
        const int f = fs - 1 + i;
        const bool oob = (f < 0) | (f > FF - 1);
        const int s0 = sgn_bit(v[i][0]), s1 = sgn_bit(v[i][1]),
                  s2 = sgn_bit(v[i][2]), s3 = sgn_bit(v[i][3]), s4 = sgn_bit(e[i]);
        const int a0 = s1 - s0 + 1;
        const int a1 = s2 - s1 + 1;
        const int a2 = s3 - s2 + 1;
        const int a3 = tail ? 1 : (s4 - s3 + 1);
        pk[i] = oob ? 0x55u : (unsigned)(a0 | (a1 << 2) | (a2 << 4) | (a3 << 6));
    }

    // ---- phase 3: compute + nontemporal-store the 8 output rows.
    // nt stores: output is never re-read; keep the 128 MiB input resident in L3.
    #pragma unroll
    for (int i = 1; i <= F_CHUNK; ++i) {
        const int g = fs + (i - 1);
        const bool isFirst = (g == 0);
        const bool isLast  = (g == FF - 1);

        const unsigned pp = pk[i - 1], pc = pk[i], pn = pk[i + 1];
        const f32x4    vp = v[i - 1],  vc = v[i],  vn = v[i + 1];

        f32x4 r;
        {
            const unsigned cp = pp & 3u, cc = pc & 3u, cn = pn & 3u;
            const bool bc = (cc == 1u) || (isFirst && cc == 0u) || (isLast && cc == 2u);
            r[0] = ((cp == 2u) ? vp[0] : 0.f) + (bc ? vc[0] : 0.f) + ((cn == 0u) ? vn[0] : 0.f);
        }
        {
            const unsigned cp = (pp >> 2) & 3u, cc = (pc >> 2) & 3u, cn = (pn >> 2) & 3u;
            const bool bc = (cc == 1u) || (isFirst && cc == 0u) || (isLast && cc == 2u);
            r[1] = ((cp == 2u) ? vp[1] : 0.f) + (bc ? vc[1] : 0.f) + ((cn == 0u) ? vn[1] : 0.f);
        }
        {
            const unsigned cp = (pp >> 4) & 3u, cc = (pc >> 4) & 3u, cn = (pn >> 4) & 3u;
            const bool bc = (cc == 1u) || (isFirst && cc == 0u) || (isLast && cc == 2u);
            r[2] = ((cp == 2u) ? vp[2] : 0.f) + (bc ? vc[2] : 0.f) + ((cn == 0u) ? vn[2] : 0.f);
        }
        {
            const unsigned cp = (pp >> 6) & 3u, cc = (pc >> 6) & 3u, cn = (pn >> 6) & 3u;
            const bool bc = (cc == 1u) || (isFirst && cc == 0u) || (isLast && cc == 2u);
            r[3] = ((cp == 2u) ? vp[3] : 0.f) + (bc ? vc[3] : 0.f) + ((cn == 0u) ? vn[3] : 0.f);
        }

        __builtin_nontemporal_store(r, reinterpret_cast<f32x4*>(dst + (size_t)g * TT));
    }
}

extern "C" void kernel_launch(void* const* d_in, const int* in_sizes, int n_in,
                              void* d_out, int out_size, void* d_ws, size_t ws_size,
                              hipStream_t stream) {
    const float* in  = (const float*)d_in[0];
    float*       out = (float*)d_out;
    // grid: (t-blocks, f-chunks, batch) = (8, 32, 16) -> 4096 blocks (16/CU)
    dim3 grid(TT / (THREADS * 4), FF / F_CHUNK, BB);
    sst_kernel<<<grid, THREADS, 0, stream>>>(in, out);
}

// Round 4
// 225.519 us; speedup vs baseline: 1.0697x; 1.0495x over previous
//
#include <hip/hip_runtime.h>

typedef float f32x4 __attribute__((ext_vector_type(4)));

#define BB 16
#define FF 256
#define TT 8192
#define F_CHUNK 8
#define ROWS (F_CHUNK + 2)
#define THREADS 256
#define TBLK (THREADS * 4)   // 1024 floats per block along t
#define LROW 1024            // LDS row: exactly 4KB -> 10 rows = 40960B -> 4 blocks/CU

__device__ __forceinline__ void dma16(const float* g, float* l) {
    // async global->LDS DMA, 16B/lane: dest = wave-uniform LDS base + lane*16
    __builtin_amdgcn_global_load_lds(
        (const __attribute__((address_space(1))) unsigned int*)g,
        (__attribute__((address_space(3))) unsigned int*)l,
        16, 0, 0);
}

__device__ __forceinline__ int sgn_bit(float x) {
    return (int)(__float_as_uint(x) >> 31);
}

// phase(x) = 0 for x>=0, pi for x<0  ->  adj code a = s(next) - s(cur) in {-1,0,1}
// out[g,t] = (a[g-1,t]==+1 ? in[g-1,t] : 0)
//          + (a[g,t]==0 || (g==0 && a<0) || (g==FF-1 && a>0) ? in[g,t] : 0)
//          + (a[g+1,t]==-1 ? in[g+1,t] : 0)
__global__ __launch_bounds__(THREADS) void sst_kernel(const float* __restrict__ in,
                                                      float* __restrict__ out) {
    __shared__ float sm[ROWS][LROW];

    const int tid    = threadIdx.x;
    const int wid    = tid >> 6;
    const int blockT = blockIdx.x * TBLK;
    const int fs     = blockIdx.y * F_CHUNK;
    const int b      = blockIdx.z;

    const float* srcB = in  + (size_t)b * FF * TT + blockT;
    float*       dstB = out + (size_t)b * FF * TT + blockT;

    const bool hasNext = (blockT + TBLK) < TT;      // next block's first element exists
    const bool lastThr = (tid == THREADS - 1);

    // ---- phase 1: 10 fire-and-forget DMAs per wave (10 KB in flight, zero VGPR cost) ----
    #pragma unroll
    for (int i = 0; i < ROWS; ++i) {
        int f = fs - 1 + i;
        f = f < 0 ? 0 : (f > FF - 1 ? FF - 1 : f);  // halo clamped; neutralized via pk sentinel
        dma16(srcB + (size_t)f * TT + tid * 4, &sm[i][wid * 256]);
    }

    // boundary sign carrier: element blockT+1024 of each row, needed only by thread 255
    float eg[ROWS];
    #pragma unroll
    for (int i = 0; i < ROWS; ++i) eg[i] = 0.0f;
    if (lastThr && hasNext) {
        #pragma unroll
        for (int i = 0; i < ROWS; ++i) {
            int f = fs - 1 + i;
            f = f < 0 ? 0 : (f > FF - 1 ? FF - 1 : f);
            eg[i] = srcB[(size_t)f * TT + TBLK];
        }
    }

    // ---- drain DMA queue + make LDS visible ----
    asm volatile("s_waitcnt vmcnt(0)" ::: "memory");
    __syncthreads();

    // ---- phase 2: read LDS, pack per-row adj codes (2-bit fields, bias +1) ----
    // field meaning: 0 -> a=-1, 1 -> a=0, 2 -> a=+1; halo rows get sentinel 0x55
    const int  tid4 = tid * 4;
    const bool tail = (blockT + tid4 + 4 >= TT);    // only the very last element overall
    const int  eidx = tid4 + 4 > LROW - 1 ? LROW - 1 : tid4 + 4;   // clamp in-row

    f32x4    v[ROWS];
    unsigned pk[ROWS];
    #pragma unroll
    for (int i = 0; i < ROWS; ++i) {
        const int f = fs - 1 + i;
        const bool oob = (f < 0) | (f > FF - 1);
        v[i] = *reinterpret_cast<const f32x4*>(&sm[i][tid4]);
        const float el = sm[i][eidx];
        const float e  = lastThr ? eg[i] : el;      // cross-block carrier for thread 255
        const int s0 = sgn_bit(v[i][0]), s1 = sgn_bit(v[i][1]),
                  s2 = sgn_bit(v[i][2]), s3 = sgn_bit(v[i][3]), s4 = sgn_bit(e);
        const int a0 = s1 - s0 + 1;
        const int a1 = s2 - s1 + 1;
        const int a2 = s3 - s2 + 1;
        const int a3 = tail ? 1 : (s4 - s3 + 1);
        pk[i] = oob ? 0x55u : (unsigned)(a0 | (a1 << 2) | (a2 << 4) | (a3 << 6));
    }

    // ---- phase 3: compute + nontemporal-store the 8 output rows ----
    #pragma unroll
    for (int i = 1; i <= F_CHUNK; ++i) {
        const int g = fs + (i - 1);
        const bool isFirst = (g == 0);
        const bool isLast  = (g == FF - 1);

        const unsigned pp = pk[i - 1], pc = pk[i], pn = pk[i + 1];
        const f32x4    vp = v[i - 1],  vc = v[i],  vn = v[i + 1];

        f32x4 r;
        {
            const unsigned cp = pp & 3u, cc = pc & 3u, cn = pn & 3u;
            const bool bc = (cc == 1u) || (isFirst && cc == 0u) || (isLast && cc == 2u);
            r[0] = ((cp == 2u) ? vp[0] : 0.f) + (bc ? vc[0] : 0.f) + ((cn == 0u) ? vn[0] : 0.f);
        }
        {
            const unsigned cp = (pp >> 2) & 3u, cc = (pc >> 2) & 3u, cn = (pn >> 2) & 3u;
            const bool bc = (cc == 1u) || (isFirst && cc == 0u) || (isLast && cc == 2u);
            r[1] = ((cp == 2u) ? vp[1] : 0.f) + (bc ? vc[1] : 0.f) + ((cn == 0u) ? vn[1] : 0.f);
        }
        {
            const unsigned cp = (pp >> 4) & 3u, cc = (pc >> 4) & 3u, cn = (pn >> 4) & 3u;
            const bool bc = (cc == 1u) || (isFirst && cc == 0u) || (isLast && cc == 2u);
            r[2] = ((cp == 2u) ? vp[2] : 0.f) + (bc ? vc[2] : 0.f) + ((cn == 0u) ? vn[2] : 0.f);
        }
        {
            const unsigned cp = (pp >> 6) & 3u, cc = (pc >> 6) & 3u, cn = (pn >> 6) & 3u;
            const bool bc = (cc == 1u) || (isFirst && cc == 0u) || (isLast && cc == 2u);
            r[3] = ((cp == 2u) ? vp[3] : 0.f) + (bc ? vc[3] : 0.f) + ((cn == 0u) ? vn[3] : 0.f);
        }

        __builtin_nontemporal_store(r, reinterpret_cast<f32x4*>(dstB + (size_t)g * TT + tid4));
    }
}

extern "C" void kernel_launch(void* const* d_in, const int* in_sizes, int n_in,
                              void* d_out, int out_size, void* d_ws, size_t ws_size,
                              hipStream_t stream) {
    const float* in  = (const float*)d_in[0];
    float*       out = (float*)d_out;
    // grid: (t-blocks, f-chunks, batch) = (8, 32, 16) -> 4096 blocks
    dim3 grid(TT / TBLK, FF / F_CHUNK, BB);
    sst_kernel<<<grid, THREADS, 0, stream>>>(in, out);
}